// Round 10
// baseline (336.253 us; speedup 1.0000x reference)
//
#include <hip/hip_runtime.h>
#include <hip/hip_bf16.h>
#include <stdint.h>

#define BB 8
#define NN 2048
#define MM 2048
#define CC 256

typedef __attribute__((ext_vector_type(8))) short short8;
typedef __attribute__((ext_vector_type(4))) float f32x4;

__device__ __forceinline__ void gl_lds16(const void* g, void* l) {
    __builtin_amdgcn_global_load_lds(
        (const __attribute__((address_space(1))) void*)g,
        (__attribute__((address_space(3))) void*)l, 16, 0, 0);
}

__device__ __forceinline__ unsigned short f2bf(float f) {
    __hip_bfloat16 h = __float2bfloat16(f);
    return *reinterpret_cast<unsigned short*>(&h);
}

// ---------------- normalize + cast + layout pre-pass (+acc zeroing) ----------------
// One wave per row of C=256 floats. Output layout = EXACT DMA source order for the
// fused kernel's linear global_load_lds staging of one 64-row/col, 64-k chunk:
//   block8KB(b, blk, t) ; within: i*1024 + (rl&15)*64 + kbL*16 + j*2
//   i = sub*4 + (rl>>4), kbL = kb ^ ((rl>>1)&3)   (bank-swizzle, proven 0-conflict)
// where t = k>>6 (k-chunk), sub = (k>>5)&1, kb = (k>>3)&3, j = k&7.
__global__ __launch_bounds__(256) void norm_cast_kernel(
    const float* __restrict__ x1, const float* __restrict__ x2,
    char* __restrict__ outA, char* __restrict__ outB,
    float* __restrict__ lsum, unsigned int* __restrict__ vcnt,
    unsigned int* __restrict__ flags, unsigned int* __restrict__ done) {
    if (blockIdx.x == 0 && threadIdx.x < 8) {
        int t = threadIdx.x;
        lsum[t] = 0.0f; vcnt[t] = 0u; flags[t] = 0u; flags[BB + t] = 0u;
        if (t == 0) *done = 0u;
    }
    int gwave = (blockIdx.x * blockDim.x + threadIdx.x) >> 6;
    int lane  = threadIdx.x & 63;
    bool isA = gwave < BB * NN;
    const float* src = isA ? x1 : x2;
    int row = isA ? gwave : gwave - BB * NN;
    float4 v = reinterpret_cast<const float4*>(src + (size_t)row * CC)[lane];
    float ss = v.x * v.x + v.y * v.y + v.z * v.z + v.w * v.w;
#pragma unroll
    for (int off = 32; off; off >>= 1) ss += __shfl_xor(ss, off);
    float inv = 1.0f / fmaxf(sqrtf(ss), 1e-8f);
    ushort4 h;
    h.x = f2bf(v.x * inv); h.y = f2bf(v.y * inv);
    h.z = f2bf(v.z * inv); h.w = f2bf(v.w * inv);
    // this lane holds k = lane*4 .. lane*4+3
    int t   = lane >> 4;          // k-chunk 0..3 (64 k each)
    int sub = (lane >> 3) & 1;    // 32-k half of chunk
    int kb  = (lane >> 1) & 3;    // 16B unit within half
    int b   = row >> 11, rb = row & 2047;
    int blk = rb >> 6, rl = rb & 63;
    int kbL = kb ^ ((rl >> 1) & 3);
    int i   = sub * 4 + (rl >> 4);
    size_t off8 = ((((size_t)b * 32 + blk) * 4 + t) << 13)
                + (i << 10) + ((rl & 15) << 6) + (kbL << 4) + ((lane & 1) << 3);
    char* p = (isA ? outA : outB) + off8;
    *reinterpret_cast<ushort4*>(p) = h;
}

// ---------------- fused MFMA cos-sim + BCE reduce + finalize ----------------
// 8192 blocks of 256 thr (4 waves), 64x64 tile each, launch_bounds(256,3):
// 3 blocks/CU (49.2 KB LDS, 170-reg cap -> no spill). b = blockIdx&7 (XCD==batch,
// A/B panels L2-resident). ALL traffic via global_load_lds DMA: z tile (16 KB)
// issued first (oldest in vm queue -> k0's counted wait stalls on z = the
// roofline resource, while the CU's other 2 blocks compute), A/B 64-k chunks
// double-buffered with per-wave-uniform counted vmcnt (never drained mid-loop).
__global__ __launch_bounds__(256, 3) void fused_mfma_kernel(
    const int*  __restrict__ z,
    const char* __restrict__ nA, const char* __restrict__ nB,
    const float* __restrict__ tptr, const float* __restrict__ bptr,
    float* __restrict__ lsum, unsigned int* __restrict__ vcnt,
    unsigned int* __restrict__ flags, unsigned int* __restrict__ done,
    float* __restrict__ out) {

    __shared__ __align__(16) char lds[49152];   // A dbuf 2x8K | B dbuf 2x8K | z 16K
    __shared__ float        s_sum[4];
    __shared__ unsigned int s_cnt[4];
    __shared__ unsigned int s_flag[2];
    char* ldsA = lds;
    char* ldsB = lds + 16384;
    char* ldsZ = lds + 32768;

    const int flat = blockIdx.x;
    const int b    = flat & 7;
    const int rest = flat >> 3;          // 0..1023
    const int nblk = rest & 31;
    const int mblk = rest >> 5;
    const int tid  = threadIdx.x, lane = tid & 63, wid = tid >> 6;
    const int wr = wid >> 1, wc = wid & 1, l15 = lane & 15;
    const int q4  = (lane >> 4) << 2;
    const int kbA = (lane >> 4) ^ ((l15 >> 1) & 3);

    // ---- z DMA first: 16 x 1KB, 4 per wave (oldest in each wave's vm queue) ----
    {
        const char* zs = (const char*)(z + ((size_t)b * NN + nblk * 64) * MM + mblk * 64);
#pragma unroll
        for (int dd = 0; dd < 4; dd++) {
            int i = wid * 4 + dd;
            gl_lds16(zs + (size_t)(i * 4 + (lane >> 4)) * (MM * 4) + (lane & 15) * 16,
                     ldsZ + i * 1024);
        }
    }

    const char* sAb = nA + ((((size_t)b * 32 + nblk) * 4) << 13);
    const char* sBb = nB + ((((size_t)b * 32 + mblk) * 4) << 13);

#define STAGE(t, s)                                                                \
    do {                                                                           \
        _Pragma("unroll")                                                          \
        for (int d = 0; d < 2; d++) {                                              \
            int i = wid * 2 + d;                                                   \
            gl_lds16(sAb + ((t) << 13) + i * 1024 + lane * 16,                     \
                     ldsA + (s) * 8192 + i * 1024);                                \
            gl_lds16(sBb + ((t) << 13) + i * 1024 + lane * 16,                     \
                     ldsB + (s) * 8192 + i * 1024);                                \
        }                                                                          \
    } while (0)

    f32x4 acc[2][2];
#pragma unroll
    for (int m = 0; m < 2; m++)
#pragma unroll
        for (int n = 0; n < 2; n++) acc[m][n] = (f32x4){0.f, 0.f, 0.f, 0.f};

#define COMPUTE(s)                                                                 \
    do {                                                                           \
        _Pragma("unroll")                                                          \
        for (int sub = 0; sub < 2; sub++) {                                        \
            short8 a0 = *reinterpret_cast<const short8*>(                          \
                ldsA + (s) * 8192 + sub * 4096 + (wr * 32 + l15) * 64 + kbA * 16); \
            short8 a1 = *reinterpret_cast<const short8*>(                          \
                ldsA + (s) * 8192 + sub * 4096 + (wr * 32 + 16 + l15) * 64 + kbA * 16); \
            short8 b0 = *reinterpret_cast<const short8*>(                          \
                ldsB + (s) * 8192 + sub * 4096 + (wc * 32 + l15) * 64 + kbA * 16); \
            short8 b1 = *reinterpret_cast<const short8*>(                          \
                ldsB + (s) * 8192 + sub * 4096 + (wc * 32 + 16 + l15) * 64 + kbA * 16); \
            acc[0][0] = __builtin_amdgcn_mfma_f32_16x16x32_bf16(a0, b0, acc[0][0], 0, 0, 0); \
            acc[0][1] = __builtin_amdgcn_mfma_f32_16x16x32_bf16(a0, b1, acc[0][1], 0, 0, 0); \
            acc[1][0] = __builtin_amdgcn_mfma_f32_16x16x32_bf16(a1, b0, acc[1][0], 0, 0, 0); \
            acc[1][1] = __builtin_amdgcn_mfma_f32_16x16x32_bf16(a1, b1, acc[1][1], 0, 0, 0); \
        }                                                                          \
    } while (0)

#define FENCE() asm volatile("" ::: "memory")
#define BAR()   do { FENCE(); __builtin_amdgcn_s_barrier(); FENCE(); } while (0)
#define VMC(n)  asm volatile("s_waitcnt vmcnt(" #n ")" ::: "memory")

    // per-wave vm queue: z(4), s0(4), s1(4)
    STAGE(0, 0);
    STAGE(1, 1);
    FENCE();

    VMC(4);  BAR();            // z + s0 done (s1 may be outstanding)
    COMPUTE(0); BAR(); STAGE(2, 0);
    VMC(4);  BAR();            // s1 done (s2 outstanding ok)
    COMPUTE(1); BAR(); STAGE(3, 1);
    VMC(4);  BAR();            // s2 done (s3 outstanding ok)
    COMPUTE(0); BAR();
    VMC(0);  BAR();            // s3 done
    COMPUTE(1);

#undef STAGE
#undef COMPUTE
#undef FENCE
#undef BAR
#undef VMC

    // ---------------- epilogue: z from LDS + log-sigmoid + reduce ----------------
    const float tv = *tptr;
    const float bs = *bptr;
    const float LOG2E = 1.4426950408889634f;
    const float LN2   = 0.6931471805599453f;

    float lsu = 0.0f;
    int   lcnt = 0;
    int   mxz = -1, mnz = 1;
#pragma unroll
    for (int mf = 0; mf < 2; mf++)
#pragma unroll
        for (int rr = 0; rr < 4; rr++)
#pragma unroll
            for (int nf = 0; nf < 2; nf++) {
                int zij = *reinterpret_cast<const int*>(
                    ldsZ + (wr * 32 + mf * 16 + q4 + rr) * 256
                         + (wc * 32 + nf * 16 + l15) * 4);
                float cs = acc[mf][nf][rr];
                float pp = fmaf(tv, cs, -bs);
                float y  = (zij < 0) ? -pp : pp;
                float e  = __builtin_amdgcn_exp2f(-fabsf(y) * LOG2E);
                float lg = __builtin_amdgcn_logf(1.0f + e);
                float ls = fminf(y, 0.0f) - LN2 * lg;
                if (zij != 0) { lsu += ls; lcnt++; }
                mxz = max(mxz, zij); mnz = min(mnz, zij);
            }

    // ---------------- block reduction (4 waves) ----------------
#pragma unroll
    for (int off = 32; off; off >>= 1) {
        lsu  += __shfl_down(lsu, off);
        lcnt += __shfl_down(lcnt, off);
    }
    unsigned long long mp = __ballot(mxz > 0);
    unsigned long long mn = __ballot(mnz < 0);

    __syncthreads();
    if (tid < 2) s_flag[tid] = 0u;
    __syncthreads();
    if (lane == 0) {
        s_sum[wid] = lsu;
        s_cnt[wid] = (unsigned int)lcnt;
        if (mp) atomicOr(&s_flag[0], 1u);
        if (mn) atomicOr(&s_flag[1], 1u);
    }
    __syncthreads();
    if (tid == 0) {
        float ts = s_sum[0] + s_sum[1] + s_sum[2] + s_sum[3];
        unsigned int tc = s_cnt[0] + s_cnt[1] + s_cnt[2] + s_cnt[3];
        atomicAdd(&lsum[b], ts);
        atomicAdd(&vcnt[b], tc);
        if (s_flag[0]) atomicOr(&flags[b], 1u);
        if (s_flag[1]) atomicOr(&flags[BB + b], 1u);
        __threadfence();
        unsigned int old = atomicAdd(done, 1u);
        if (old == gridDim.x - 1) {
            __threadfence();
            double s = 0.0, c = 0.0;
#pragma unroll
            for (int bb = 0; bb < BB; bb++) {
                unsigned int fp = atomicOr(&flags[bb], 0u);
                unsigned int fn = atomicOr(&flags[BB + bb], 0u);
                float        sv = atomicAdd(&lsum[bb], 0.0f);
                unsigned int cv = atomicAdd(&vcnt[bb], 0u);
                if (fp && fn) { s += (double)sv; c += (double)cv; }
            }
            out[0] = (float)(-s / c);
        }
    }
}

extern "C" void kernel_launch(void* const* d_in, const int* in_sizes, int n_in,
                              void* d_out, int out_size, void* d_ws, size_t ws_size,
                              hipStream_t stream) {
    const int*   z   = (const int*)  d_in[0];
    const float* x1  = (const float*)d_in[1];
    const float* x2  = (const float*)d_in[2];
    const float* tp  = (const float*)d_in[3];
    const float* bp  = (const float*)d_in[4];
    float* out = (float*)d_out;

    char* ws = (char*)d_ws;
    char*  normA = ws;                                  // 8 MiB
    char*  normB = ws + (size_t)BB * NN * 512;          // 8 MiB
    char*  accb  = ws + (size_t)BB * (NN + MM) * 512;
    float*        lsum  = (float*)accb;
    unsigned int* vcnt  = (unsigned int*)(accb + 64);
    unsigned int* flags = (unsigned int*)(accb + 128);
    unsigned int* done  = (unsigned int*)(accb + 256);

    hipLaunchKernelGGL(norm_cast_kernel, dim3(BB * (NN + MM) / 4), dim3(256), 0, stream,
                       x1, x2, normA, normB, lsum, vcnt, flags, done);

    hipLaunchKernelGGL(fused_mfma_kernel, dim3(8192), dim3(256), 0, stream,
                       z, normA, normB, tp, bp, lsum, vcnt, flags, done, out);
}

// Round 11
// 63.453 us; speedup vs baseline: 5.2993x; 5.2993x over previous
//
#include <hip/hip_runtime.h>
#include <hip/hip_bf16.h>
#include <stdint.h>

#define BB 8
#define NN 2048
#define MM 2048
#define CC 256

typedef __attribute__((ext_vector_type(8))) short short8;
typedef __attribute__((ext_vector_type(4))) float f32x4;

__device__ __forceinline__ void gl_lds16(const void* g, void* l) {
    __builtin_amdgcn_global_load_lds(
        (const __attribute__((address_space(1))) void*)g,
        (__attribute__((address_space(3))) void*)l, 16, 0, 0);
}

__device__ __forceinline__ unsigned short f2bf(float f) {
    __hip_bfloat16 h = __float2bfloat16(f);
    return *reinterpret_cast<unsigned short*>(&h);
}

// ---------------- normalize + cast + layout pre-pass (+acc zeroing) ----------------
// One wave per row of C=256 floats.  (R5 layouts, proven 0-conflict / coalesced.)
// A layout (bytes):  row*512 + c*64 + kbL*16 + (lane&1)*8,  kbL = kb ^ ((row>>1)&3)
// B layout (bytes):  batch*1MiB + ((r>>4)*8 + c)*1024 + kbL*256 + (r&15)*16 + ...
__global__ __launch_bounds__(256) void norm_cast_kernel(
    const float* __restrict__ x1, const float* __restrict__ x2,
    char* __restrict__ outA, char* __restrict__ outB,
    float* __restrict__ lsum, unsigned int* __restrict__ vcnt,
    unsigned int* __restrict__ flags, unsigned int* __restrict__ done) {
    if (blockIdx.x == 0 && threadIdx.x < 8) {
        int t = threadIdx.x;
        lsum[t] = 0.0f; vcnt[t] = 0u; flags[t] = 0u; flags[BB + t] = 0u;
        if (t == 0) *done = 0u;
    }
    int gwave = (blockIdx.x * blockDim.x + threadIdx.x) >> 6;
    int lane  = threadIdx.x & 63;
    bool isA = gwave < BB * NN;
    const float* src = isA ? x1 : x2;
    int row = isA ? gwave : gwave - BB * NN;
    float4 v = reinterpret_cast<const float4*>(src + (size_t)row * CC)[lane];
    float ss = v.x * v.x + v.y * v.y + v.z * v.z + v.w * v.w;
#pragma unroll
    for (int off = 32; off; off >>= 1) ss += __shfl_xor(ss, off);
    float inv = 1.0f / fmaxf(sqrtf(ss), 1e-8f);
    ushort4 h;
    h.x = f2bf(v.x * inv); h.y = f2bf(v.y * inv);
    h.z = f2bf(v.z * inv); h.w = f2bf(v.w * inv);
    int c   = lane >> 3;              // k-chunk 0..7
    int kb  = (lane >> 1) & 3;        // 16B k-unit
    int kbL = kb ^ ((row >> 1) & 3);  // bank swizzle
    char* p;
    if (isA) {
        p = outA + (size_t)row * 512 + c * 64 + kbL * 16 + (lane & 1) * 8;
    } else {
        int b = row >> 11, r = row & 2047;
        p = outB + (size_t)b * 1048576 + (size_t)((r >> 4) * 8 + c) * 1024
                 + kbL * 256 + (r & 15) * 16 + (lane & 1) * 8;
    }
    *reinterpret_cast<ushort4*>(p) = h;
}

// ---------------- fused MFMA cos-sim + BCE reduce + finalize ----------------
// R5 structure: 512 blocks (XCD-swizzled b=blockIdx&7, A/B L2-resident), each
// block owns a 128-row A-panel full-K in LDS (64 KB, staged once) and iterates
// 4 m-tiles of 128 cols. Deltas vs R5: (1) NO reg cap — bulk-issue all 16 B
// fragments + 32 z scalars per tile, pinned by sched_barrier(0) so the compiler
// cannot serialize them into the MFMA chain (R5's VGPR=52 pathology); (2)
// finalize folded in via done-ticket; (3) exp2-domain epilogue.
__global__ __launch_bounds__(512) void fused_mfma_kernel(
    const int*  __restrict__ z,
    const char* __restrict__ nA, const char* __restrict__ nB,
    const float* __restrict__ tptr, const float* __restrict__ bptr,
    float* __restrict__ lsum, unsigned int* __restrict__ vcnt,
    unsigned int* __restrict__ flags, unsigned int* __restrict__ done,
    float* __restrict__ out) {

    __shared__ __align__(16) char ldsA[65536];   // 8 k-chunks x 128 rows x 64 B
    __shared__ float        s_sum[8];
    __shared__ unsigned int s_cnt[8];
    __shared__ unsigned int s_flag[2];

    const int flat = blockIdx.x;
    const int b    = flat & 7;           // XCD id == batch
    const int rest = flat >> 3;          // 0..63
    const int n0   = (rest & 15) * 128;  // 16 n-panels of 128 rows
    const int mq   = rest >> 4;          // 0..3 (m-quarter: 4 tiles of 128)
    const int tid  = threadIdx.x, lane = tid & 63, wid = tid >> 6;
    const int wr = wid >> 2, wc = wid & 3, l15 = lane & 15;
    const int q4  = (lane >> 4) << 2;
    const int kbL = (lane >> 4) ^ ((l15 >> 1) & 3);

    // ---- A staging: wave `wid` stages k-chunk c=wid, 128 rows (8 x 1 KiB) ----
    {
        const char* src = nA + ((size_t)b * NN + n0) * 512
                        + (size_t)(lane >> 2) * 512 + wid * 64 + (lane & 3) * 16;
        char* dst = ldsA + wid * 8192;
#pragma unroll
        for (int g = 0; g < 8; g++)
            gl_lds16(src + (size_t)g * 8192, dst + g * 1024);
    }

    const char* gB0 = nB + (size_t)b * 1048576 + (size_t)mq * 262144
                    + kbL * 256 + l15 * 16;
    const int* zb = z + ((size_t)b * NN + n0 + wr * 64 + q4) * MM
                      + mq * 512 + wc * 32 + l15;

    const float tv = *tptr;
    const float bs = *bptr;
    const float LOG2E = 1.4426950408889634f;
    const float LN2   = 0.6931471805599453f;

    __syncthreads();   // A-slab resident

    float lsu = 0.0f;
    int   lcnt = 0;
    int   mxz = -1, mnz = 1;

#pragma unroll
    for (int mt = 0; mt < 4; mt++) {
        const char* gBt = gB0 + mt * 65536;

        // ---- bulk-issue phase: 16 B fragments + 32 z scalars, all in flight ----
        short8 bfr[8][2];
#pragma unroll
        for (int c = 0; c < 8; c++)
#pragma unroll
            for (int n = 0; n < 2; n++)
                bfr[c][n] = *reinterpret_cast<const short8*>(
                    gBt + (wc * 2 + n) * 8192 + c * 1024);

        int zr[32];
#pragma unroll
        for (int m = 0; m < 4; m++)
#pragma unroll
            for (int r = 0; r < 4; r++)
#pragma unroll
                for (int n = 0; n < 2; n++)
                    zr[(m * 4 + r) * 2 + n] = zb[mt * 128 + (m * 16 + r) * MM + n * 16];

        // pin: loads above may not sink past this point
        __builtin_amdgcn_sched_barrier(0);

        // ---- MFMA over full K (wave-tile 64x32) ----
        f32x4 acc[4][2] = {};
#pragma unroll
        for (int c = 0; c < 8; c++) {
            short8 af[4];
#pragma unroll
            for (int m = 0; m < 4; m++)
                af[m] = *reinterpret_cast<const short8*>(
                    ldsA + c * 8192 + (wr * 64 + m * 16 + l15) * 64 + kbL * 16);
#pragma unroll
            for (int m = 0; m < 4; m++) {
                acc[m][0] = __builtin_amdgcn_mfma_f32_16x16x32_bf16(af[m], bfr[c][0], acc[m][0], 0, 0, 0);
                acc[m][1] = __builtin_amdgcn_mfma_f32_16x16x32_bf16(af[m], bfr[c][1], acc[m][1], 0, 0, 0);
            }
        }

        // ---- fused epilogue (exp2-domain log-sigmoid) ----
#pragma unroll
        for (int m = 0; m < 4; m++)
#pragma unroll
            for (int r = 0; r < 4; r++)
#pragma unroll
                for (int n = 0; n < 2; n++) {
                    int zij = zr[(m * 4 + r) * 2 + n];
                    float cs = acc[m][n][r];
                    float pp = fmaf(tv, cs, -bs);
                    float y  = (zij < 0) ? -pp : pp;
                    float e  = __builtin_amdgcn_exp2f(-fabsf(y) * LOG2E);
                    float lg = __builtin_amdgcn_logf(1.0f + e);
                    float ls = fminf(y, 0.0f) - LN2 * lg;
                    if (zij != 0) { lsu += ls; lcnt++; }
                    mxz = max(mxz, zij); mnz = min(mnz, zij);
                }
    }

    // ---------------- block reduction ----------------
#pragma unroll
    for (int off = 32; off; off >>= 1) {
        lsu  += __shfl_down(lsu, off);
        lcnt += __shfl_down(lcnt, off);
    }
    unsigned long long mp = __ballot(mxz > 0);
    unsigned long long mn = __ballot(mnz < 0);

    __syncthreads();
    if (tid < 2) s_flag[tid] = 0u;
    __syncthreads();
    if (lane == 0) {
        s_sum[wid] = lsu;
        s_cnt[wid] = (unsigned int)lcnt;
        if (mp) atomicOr(&s_flag[0], 1u);
        if (mn) atomicOr(&s_flag[1], 1u);
    }
    __syncthreads();
    if (tid == 0) {
        float ts = 0.f; unsigned int tc = 0u;
#pragma unroll
        for (int w = 0; w < 8; w++) { ts += s_sum[w]; tc += s_cnt[w]; }
        atomicAdd(&lsum[b], ts);
        atomicAdd(&vcnt[b], tc);
        if (s_flag[0]) atomicOr(&flags[b], 1u);
        if (s_flag[1]) atomicOr(&flags[BB + b], 1u);
        __threadfence();
        unsigned int old = atomicAdd(done, 1u);
        if (old == gridDim.x - 1) {
            __threadfence();
            double s = 0.0, c = 0.0;
#pragma unroll
            for (int bb = 0; bb < BB; bb++) {
                unsigned int fp = atomicOr(&flags[bb], 0u);
                unsigned int fn = atomicOr(&flags[BB + bb], 0u);
                float        sv = atomicAdd(&lsum[bb], 0.0f);
                unsigned int cv = atomicAdd(&vcnt[bb], 0u);
                if (fp && fn) { s += (double)sv; c += (double)cv; }
            }
            out[0] = (float)(-s / c);
        }
    }
}

extern "C" void kernel_launch(void* const* d_in, const int* in_sizes, int n_in,
                              void* d_out, int out_size, void* d_ws, size_t ws_size,
                              hipStream_t stream) {
    const int*   z   = (const int*)  d_in[0];
    const float* x1  = (const float*)d_in[1];
    const float* x2  = (const float*)d_in[2];
    const float* tp  = (const float*)d_in[3];
    const float* bp  = (const float*)d_in[4];
    float* out = (float*)d_out;

    char* ws = (char*)d_ws;
    char*  normA = ws;                                  // 8 MiB
    char*  normB = ws + (size_t)BB * NN * 512;          // 8 MiB
    char*  accb  = ws + (size_t)BB * (NN + MM) * 512;
    float*        lsum  = (float*)accb;
    unsigned int* vcnt  = (unsigned int*)(accb + 64);
    unsigned int* flags = (unsigned int*)(accb + 128);
    unsigned int* done  = (unsigned int*)(accb + 256);

    hipLaunchKernelGGL(norm_cast_kernel, dim3(BB * (NN + MM) / 4), dim3(256), 0, stream,
                       x1, x2, normA, normB, lsum, vcnt, flags, done);

    hipLaunchKernelGGL(fused_mfma_kernel, dim3(512), dim3(512), 0, stream,
                       z, normA, normB, tp, bp, lsum, vcnt, flags, done, out);
}